// Round 14
// baseline (38.816 us; speedup 1.0000x reference)
//
#include <hip/hip_runtime.h>

// PS-RoI-Align (torchvision ps_roi_align semantics).
// feat: [4, 784, 112, 112] fp32; rois: [K,5]; out: [K, 16, 7, 7] fp32.
//
// R13: producer-consumer wave specialization (ring of 3 LDS plane slots).
//   Scoreboard R5-R12: ALL lockstep staging schedules pin at ~2.7us/plane/CU
//   (4.65 TB/s); m13's 6.29 TB/s differs only in CONTINUOUS issue. So:
//   2 producer waves stream planes into a 3-slot ring via global_load_lds,
//   flag ready after their OWN per-wave vmcnt(0) (no block-wide drain);
//   8 consumer waves spin on ready, compute (R5 body), count-in to free.
//   No __syncthreads after init -> issue decoupled from compute barriers.
//   Protocol: done[s]==8 means slot free; producer spins, resets to 0,
//   issues 49 1KB DMA loads, vmcnt(0), sets ready[s]=i+1 (seq -> ABA-safe).
//   Consumer i spins ready[i%3]==i+1, computes, lane0 atomicAdd done.
//   Producers of planes i,i+1 are different waves on different slots;
//   slot reuse (i+3) is guarded by done-spin. LDS ds ops in-order per wave.

#define PP 7
#define SR 2
#define SCALEF 0.0625f

constexpr int Cc     = 784;            // Cout * P * P
constexpr int Hh     = 112;
constexpr int Ww     = 112;
constexpr int PLANE  = Hh * Ww;        // 12544 floats = 50176 B
constexpr int CHUNKS = 49;             // 1KB chunks (64 lanes x 16 B)
constexpr int NBLK   = 256;            // 1 block / CU
constexpr int NPROD  = 2;              // producer waves
constexpr int NCONS  = 8;              // consumer waves
constexpr int TPB    = (NPROD + NCONS) * 64;   // 640
constexpr int SLOTS  = 3;
constexpr int RPT    = 2;              // rois per consumer thread (K <= 1024)

__global__ __launch_bounds__(TPB) void psroi_pc_kernel(
    const float* __restrict__ feat,
    const float* __restrict__ rois,
    float* __restrict__ out,
    int K, int nplanes)
{
    __shared__ float buf[SLOTS][PLANE];    // 150528 B
    __shared__ int ready[SLOTS];           // plane seq+1 when slot loaded
    __shared__ int done[SLOTS];            // consumer-done count (8 = free)

    int tid  = threadIdx.x;
    int wave = tid >> 6;
    int lane = tid & 63;

    if (tid < SLOTS) { ready[tid] = 0; done[tid] = NCONS; }
    __syncthreads();                       // the ONLY block-wide barrier

    // balanced contiguous partition: blocks 0..63 get 13 planes, rest 12
    int per   = nplanes / NBLK;
    int rem   = nplanes % NBLK;
    int bid   = blockIdx.x;
    int start = bid * per + min(bid, rem);
    int cnt   = per + (bid < rem ? 1 : 0);

    if (wave < NPROD) {
        // ======== PRODUCER: planes i = wave, wave+NPROD, ... ========
        for (int i = wave; i < cnt; i += NPROD) {
            int s = i % SLOTS;
            // wait until slot free (all lanes broadcast-read same addr)
            while (*(volatile int*)&done[s] != NCONS)
                __builtin_amdgcn_s_sleep(2);
            if (lane == 0) *(volatile int*)&done[s] = 0;   // claim
            // issue 49 async DMA loads (this wave only)
            const float* src = feat + (size_t)(start + i) * PLANE;
            for (int j = 0; j < CHUNKS; ++j) {
                __builtin_amdgcn_global_load_lds(
                    (const __attribute__((address_space(1))) void*)(src + j * 256 + lane * 4),
                    (__attribute__((address_space(3))) void*)(&buf[s][j * 256]),
                    16, 0, 0);
            }
            asm volatile("s_waitcnt vmcnt(0)" ::: "memory");   // OWN loads only
            if (lane == 0) *(volatile int*)&ready[s] = i + 1;  // publish
        }
    } else {
        // ======== CONSUMER ========
        int ctid = tid - NPROD * 64;       // 0..511

        // parse roi params once into registers (R5 scheme)
        int   rb[RPT];
        float x1[RPT], y1[RPT], bsh[RPT], bsw[RPT];
#pragma unroll
        for (int j = 0; j < RPT; ++j) {
            int k = ctid + j * (NCONS * 64);
            if (k < K) {
                const float* r = rois + (size_t)k * 5;
                rb[j]  = (int)r[0];
                x1[j]  = r[1] * SCALEF - 0.5f;
                y1[j]  = r[2] * SCALEF - 0.5f;
                float rw = fmaxf(r[3] * SCALEF - 0.5f - x1[j], 0.1f);
                float rh = fmaxf(r[4] * SCALEF - 0.5f - y1[j], 0.1f);
                bsh[j] = rh * (1.0f / (float)PP);
                bsw[j] = rw * (1.0f / (float)PP);
            } else {
                rb[j] = -1;
            }
        }

        for (int i = 0; i < cnt; ++i) {
            int s = i % SLOTS;
            while (*(volatile int*)&ready[s] != i + 1)
                __builtin_amdgcn_s_sleep(2);
            asm volatile("" ::: "memory");  // no hoisting of data reads

            int p  = start + i;
            int b  = p / Cc;
            int c  = p % Cc;
            int pw = c % PP;
            int ph = (c % (PP * PP)) / PP;
            const float* pl = buf[s];

#pragma unroll
            for (int j = 0; j < RPT; ++j) {
                if (rb[j] != b) continue;
                float acc = 0.0f;
#pragma unroll
                for (int iy = 0; iy < SR; ++iy) {
                    float gy = ((float)iy + 0.5f) / (float)SR;
                    float y  = y1[j] + ((float)ph + gy) * bsh[j];
                    bool  vy = (y >= -1.0f) && (y <= (float)Hh);
                    float yc = fminf(fmaxf(y, 0.0f), (float)(Hh - 1));
                    int   yl = (int)yc;            // yc >= 0 -> trunc == floor
                    int   yh = min(yl + 1, Hh - 1);
                    float ly = yc - (float)yl;
                    float hy = 1.0f - ly;
#pragma unroll
                    for (int ix = 0; ix < SR; ++ix) {
                        float gx = ((float)ix + 0.5f) / (float)SR;
                        float x  = x1[j] + ((float)pw + gx) * bsw[j];
                        bool  vx = (x >= -1.0f) && (x <= (float)Ww);
                        float xc = fminf(fmaxf(x, 0.0f), (float)(Ww - 1));
                        int   xl = (int)xc;
                        int   xh = min(xl + 1, Ww - 1);
                        float lx = xc - (float)xl;
                        float hx = 1.0f - lx;

                        float v = hy * hx * pl[yl * Ww + xl]
                                + hy * lx * pl[yl * Ww + xh]
                                + ly * hx * pl[yh * Ww + xl]
                                + ly * lx * pl[yh * Ww + xh];
                        acc += (vy && vx) ? v : 0.0f;
                    }
                }
                int k = ctid + j * (NCONS * 64);
                out[(size_t)k * Cc + c] = acc * (1.0f / (float)(SR * SR));
            }

            // this wave's LDS reads are in-order before the atomic
            asm volatile("s_waitcnt lgkmcnt(0)" ::: "memory");
            if (lane == 0) atomicAdd(&done[s], 1);
        }
    }
}

extern "C" void kernel_launch(void* const* d_in, const int* in_sizes, int n_in,
                              void* d_out, int out_size, void* d_ws, size_t ws_size,
                              hipStream_t stream) {
    const float* feat = (const float*)d_in[0];
    const float* rois = (const float*)d_in[1];
    float* out = (float*)d_out;

    int K = in_sizes[1] / 5;
    int nplanes = in_sizes[0] / PLANE;          // N * Cc = 3136
    psroi_pc_kernel<<<NBLK, TPB, 0, stream>>>(feat, rois, out, K, nplanes);
}